// Round 1
// baseline (503.540 us; speedup 1.0000x reference)
//
#include <hip/hip_runtime.h>
#include <math.h>

#define DIN 640
#define DH 1024
#define DOUT 128
#define CODEDIM 256
#define NE 8
#define NB 8
#define NT 1024
#define TAU_INV 10.0f
#define FEPS 1e-8f

// out layout: full_output[8*1024*1024], aux[1], div[1], ent[8], mean[8], std[8]
#define AUX_OFF  8388608
#define DIV_OFF  8388609
#define ENT_OFF  8388610
#define MEAN_OFF 8388618
#define STD_OFF  8388626

typedef __bf16 bf16;
typedef bf16 bf16x4 __attribute__((ext_vector_type(4)));
typedef bf16 bf16x8 __attribute__((ext_vector_type(8)));
typedef float f32x16 __attribute__((ext_vector_type(16)));

// ---------------- block reduction helpers (blockDim multiple of 64) ----------
__device__ __forceinline__ float blk_sum(float v, float* sb) {
  #pragma unroll
  for (int o = 32; o > 0; o >>= 1) v += __shfl_down(v, o, 64);
  __syncthreads();
  if ((threadIdx.x & 63) == 0) sb[threadIdx.x >> 6] = v;
  __syncthreads();
  float tot = 0.f;
  int nw = blockDim.x >> 6;
  for (int i = 0; i < nw; ++i) tot += sb[i];
  return tot;
}

__device__ __forceinline__ float blk_max(float v, float* sb) {
  #pragma unroll
  for (int o = 32; o > 0; o >>= 1) v = fmaxf(v, __shfl_down(v, o, 64));
  __syncthreads();
  if ((threadIdx.x & 63) == 0) sb[threadIdx.x >> 6] = v;
  __syncthreads();
  float m = -3.0e38f;
  int nw = blockDim.x >> 6;
  for (int i = 0; i < nw; ++i) m = fmaxf(m, sb[i]);
  return m;
}

// ---------------- importance softmax + entropy/mean/std ---------------------
__global__ void k_imp(const float* __restrict__ fi, float* __restrict__ imp,
                      float* __restrict__ out) {
  __shared__ float sb[8];
  int e = blockIdx.x, tid = threadIdx.x;
  int d2v = tid + 512;
  float v0 = fi[e*DIN + tid] * 2.0f;          // /temp, temp = 0.5
  float v1 = fi[e*DIN + tid + 256] * 2.0f;
  float v2 = (d2v < DIN) ? fi[e*DIN + d2v] * 2.0f : -3.0e38f;
  float m = blk_max(fmaxf(v0, fmaxf(v1, v2)), sb);
  float e0 = expf(v0 - m), e1 = expf(v1 - m);
  float e2 = (d2v < DIN) ? expf(v2 - m) : 0.f;
  float s = blk_sum(e0 + e1 + e2, sb);
  float inv = 1.0f / s;
  float p0 = e0*inv, p1 = e1*inv, p2 = e2*inv;
  imp[e*DIN + tid] = p0;
  imp[e*DIN + tid + 256] = p1;
  if (d2v < DIN) imp[e*DIN + d2v] = p2;
  float ok2 = (d2v < DIN) ? 1.f : 0.f;
  float sp  = p0 + p1 + ok2*p2;
  float sp2 = p0*p0 + p1*p1 + ok2*p2*p2;
  float se  = p0*logf(p0 + FEPS) + p1*logf(p1 + FEPS) + ok2*p2*logf(p2 + FEPS);
  sp  = blk_sum(sp, sb);
  sp2 = blk_sum(sp2, sb);
  se  = blk_sum(se, sb);
  if (tid == 0) {
    out[ENT_OFF + e]  = -se;
    out[MEAN_OFF + e] = sp * (1.0f/DIN);
    float var = (sp2 - sp*sp*(1.0f/DIN)) * (1.0f/(DIN-1));
    out[STD_OFF + e]  = sqrtf(fmaxf(var, 0.f));
  }
}

// ---------------- anchor normalize + diversity loss --------------------------
__global__ void k_anchor_div(const float* __restrict__ ca, const float* __restrict__ fi,
                             float* __restrict__ anch, float* __restrict__ out) {
  __shared__ float sb[8];
  __shared__ float sd[256];
  int tid = threadIdx.x;
  for (int e = 0; e < NE; ++e) {
    float x = ca[e*CODEDIM + tid];
    float ss = blk_sum(x*x, sb);
    anch[e*CODEDIM + tid] = x / fmaxf(sqrtf(ss), 1e-12f);
  }
  // diversity: sim = fi @ fi^T, off-diag squared sum / 56
  int p = tid >> 2, q = tid & 3;     // pair p in 0..63, quarter q
  int i = p >> 3, j = p & 7;
  float dot = 0.f;
  for (int d = q*160; d < q*160 + 160; ++d) dot += fi[i*DIN + d] * fi[j*DIN + d];
  sd[tid] = dot;
  __syncthreads();
  if (tid < 64) {
    float s = sd[tid*4] + sd[tid*4+1] + sd[tid*4+2] + sd[tid*4+3];
    int ii = tid >> 3, jj = tid & 7;
    float val = (ii != jj) ? s*s : 0.f;
    #pragma unroll
    for (int o = 32; o > 0; o >>= 1) val += __shfl_down(val, o, 64);
    if (tid == 0) out[DIV_OFF] = val * (1.0f/56.0f);
  }
}

// ---------------- tiled transpose + f32->bf16: src[e][R][C] -> dst[e][C][R] --
__global__ void k_transpose(const float* __restrict__ src, bf16* __restrict__ dst,
                            int R, int C) {
  __shared__ float tile[64][65];
  int c0 = blockIdx.x*64, r0 = blockIdx.y*64;
  int ee = blockIdx.z;
  const float* s = src + (size_t)ee*R*C;
  bf16* d = dst + (size_t)ee*C*R;
  int tx = threadIdx.x & 63, ty = threadIdx.x >> 6;
  #pragma unroll
  for (int p = 0; p < 16; ++p) {
    int r = p*4 + ty;
    tile[r][tx] = s[(size_t)(r0 + r)*C + c0 + tx];
  }
  __syncthreads();
  #pragma unroll
  for (int p = 0; p < 16; ++p) {
    int cr = p*4 + ty;
    d[(size_t)(c0 + cr)*R + r0 + tx] = (bf16)tile[tx][cr];
  }
}

// ---------------- router: cosine logits + gumbel softmax ---------------------
__global__ void k_router(const float* __restrict__ ce, const float* __restrict__ gn,
                         const float* __restrict__ anch, float* __restrict__ ew) {
  __shared__ float anc[NE*CODEDIM];
  int tid = threadIdx.x;
  for (int i2 = tid; i2 < NE*CODEDIM; i2 += 256) anc[i2] = anch[i2];
  __syncthreads();
  int wv = tid >> 6, lane = tid & 63;
  int token = blockIdx.x*4 + wv;
  float4 x = *(const float4*)(ce + (size_t)token*CODEDIM + lane*4);
  float ss = x.x*x.x + x.y*x.y + x.z*x.z + x.w*x.w;
  #pragma unroll
  for (int o = 1; o < 64; o <<= 1) ss += __shfl_xor(ss, o, 64);
  float inv = 1.0f / fmaxf(sqrtf(ss), 1e-12f);
  const float* g = gn + (size_t)token*NE;
  float z[8];
  float m = -3.0e38f;
  #pragma unroll
  for (int e2 = 0; e2 < NE; ++e2) {
    const float* a = anc + e2*CODEDIM + lane*4;
    float d = x.x*a[0] + x.y*a[1] + x.z*a[2] + x.w*a[3];
    #pragma unroll
    for (int o = 1; o < 64; o <<= 1) d += __shfl_xor(d, o, 64);
    z[e2] = (d*inv + g[e2]) * TAU_INV;
    m = fmaxf(m, z[e2]);
  }
  float ssum = 0.f;
  float pz[8];
  #pragma unroll
  for (int e2 = 0; e2 < NE; ++e2) { pz[e2] = expf(z[e2] - m); ssum += pz[e2]; }
  float num = 0.f;
  #pragma unroll
  for (int e2 = 0; e2 < NE; ++e2) num = (lane == e2) ? pz[e2] : num;  // static idx
  if (lane < NE) ew[(size_t)token*NE + lane] = num / ssum;
}

// ---------------- fused per-(b,e,64-token-tile) MoE MLP ----------------------
// 512 threads = 8 waves = 2 row-groups (32 rows) x 4 col-groups (32 cols).
// GEMM1: X[64,640]bf16 (LDS, swizzled) @ W1T-frag -> gelu -> Hs[64,128]bf16 (LDS)
// GEMM2: Hs @ W2T-frag accumulated over 8 chunks -> +b2, *gate -> out f32
__global__ __launch_bounds__(512, 2)
void k_main(const float* __restrict__ h, const bf16* __restrict__ w1t,
            const bf16* __restrict__ w2t, const float* __restrict__ imp,
            const float* __restrict__ b1, const float* __restrict__ b2,
            const float* __restrict__ ew, float* __restrict__ out) {
  __shared__ bf16 XsF[64*DIN];     // 80 KiB, XOR-swizzled rows (stride 1280B)
  __shared__ bf16 HsF[64*128];     // 16 KiB, XOR-swizzled rows (stride 256B)
  __shared__ float imp_s[DIN];
  __shared__ float b1_s[DH];
  __shared__ float b2_s[DOUT];
  int bid = blockIdx.x;
  int tt = bid & 15, e = (bid >> 4) & 7, b = bid >> 7;
  int t0 = tt * 64;
  int tid = threadIdx.x;
  for (int i = tid; i < DIN; i += 512) imp_s[i] = imp[e*DIN + i];
  for (int i = tid; i < DH; i += 512)  b1_s[i]  = b1[e*DH + i];
  if (tid < DOUT) b2_s[tid] = b2[e*DOUT + tid];
  __syncthreads();
  // stage X = h * importance as bf16 (coalesced float4 reads)
  const float* hb = h + (size_t)(b*NT + t0) * DIN;
  for (int i = tid; i < 64*(DIN/4); i += 512) {
    int row = i / (DIN/4);
    int c4 = (i - row*(DIN/4)) * 4;
    float4 v = *(const float4*)(hb + (size_t)row*DIN + c4);
    bf16x4 bv;
    bv[0] = (bf16)(v.x * imp_s[c4]);
    bv[1] = (bf16)(v.y * imp_s[c4+1]);
    bv[2] = (bf16)(v.z * imp_s[c4+2]);
    bv[3] = (bf16)(v.w * imp_s[c4+3]);
    unsigned wb = (unsigned)(row*(DIN*2) + c4*2) ^ ((unsigned)(row & 7) << 4);
    *(bf16x4*)((char*)XsF + wb) = bv;
  }
  __syncthreads();
  int lane = tid & 63, w = tid >> 6;
  int wr = w >> 2, wc = w & 3;
  int l31 = lane & 31, hh = lane >> 5;
  int arow = 32*wr + l31;
  unsigned xr = (unsigned)(arow & 7) << 4;
  unsigned abaseX = (unsigned)(arow*(DIN*2) + 16*hh);
  unsigned abaseH = (unsigned)(arow*256 + 16*hh);
  int colg = wc*32 + l31;                     // chunk-local col / out col
  f32x16 acc2 = {};
  const bf16* w1e = w1t + (size_t)e*DH*DIN;
  const bf16* w2e = w2t + (size_t)e*DOUT*DH;
  const bf16* pB2base = w2e + (size_t)colg*DH + 8*hh;
  for (int cc = 0; cc < 8; ++cc) {
    f32x16 acc1 = {};
    const bf16* pB = w1e + (size_t)(cc*128 + colg)*DIN + 8*hh;
    #pragma unroll 4
    for (int ks = 0; ks < DIN/16; ++ks) {
      bf16x8 af = *(const bf16x8*)((const char*)XsF + ((abaseX + 32u*ks) ^ xr));
      bf16x8 bfr = *(const bf16x8*)(pB + 16*ks);
      acc1 = __builtin_amdgcn_mfma_f32_32x32x16_bf16(af, bfr, acc1, 0, 0, 0);
    }
    // epilogue: +b1, exact GELU, bf16 -> Hs (swizzled)
    float bb = b1_s[cc*128 + colg];
    #pragma unroll
    for (int r = 0; r < 16; ++r) {
      int rowa = 32*wr + (r & 3) + 8*(r >> 2) + 4*hh;   // verified C/D row map
      float xv = acc1[r] + bb;
      float gv = 0.5f * xv * (1.0f + erff(xv * 0.70710678118654752f));
      unsigned wb = (unsigned)(rowa*256 + colg*2) ^ ((unsigned)(rowa & 7) << 4);
      *(bf16*)((char*)HsF + wb) = (bf16)gv;
    }
    __syncthreads();
    const bf16* pB2 = pB2base + cc*128;
    #pragma unroll
    for (int kk = 0; kk < 8; ++kk) {
      bf16x8 a2 = *(const bf16x8*)((const char*)HsF + ((abaseH + 32u*kk) ^ xr));
      bf16x8 b2r = *(const bf16x8*)(pB2 + 16*kk);
      acc2 = __builtin_amdgcn_mfma_f32_32x32x16_bf16(a2, b2r, acc2, 0, 0, 0);
    }
    __syncthreads();
  }
  float bb2 = b2_s[colg];
  #pragma unroll
  for (int r = 0; r < 16; ++r) {
    int rowa = 32*wr + (r & 3) + 8*(r >> 2) + 4*hh;
    int t = t0 + rowa;
    float gate = ew[(size_t)(b*NT + t)*NE + e];
    out[(size_t)(b*NT + t)*(NE*DOUT) + e*DOUT + colg] = (acc2[r] + bb2) * gate;
  }
}

// ---------------- expert counts + partial sums --------------------------------
__global__ void k_counts(const float* __restrict__ ew, float* __restrict__ counts,
                         float* __restrict__ partials) {
  __shared__ float sb[4];
  int g2 = blockIdx.x*256 + threadIdx.x;   // (t,e) flat, 0..8191
  float c = 0.f;
  #pragma unroll
  for (int b = 0; b < NB; ++b) c += ew[b*(NT*NE) + g2];
  counts[g2] = c;
  float tot = blk_sum(c, sb);
  if (threadIdx.x == 0) partials[blockIdx.x] = tot;
}

// ---------------- aux loss ----------------------------------------------------
__global__ void k_aux(const float* __restrict__ counts, const float* __restrict__ partials,
                      float* __restrict__ out) {
  __shared__ float sb[4];
  int tid = threadIdx.x;
  float pv = (tid < 32) ? partials[tid] : 0.f;
  float total = blk_sum(pv, sb);
  float invt = 1.0f / (total + FEPS);
  float sq = 0.f, ent = 0.f;
  for (int i2 = tid; i2 < NT*NE; i2 += 256) {
    float c = counts[i2];
    sq += c*c;
    float ld = c * invt;
    ent -= ld * logf(ld + FEPS);
  }
  sq = blk_sum(sq, sb);
  ent = blk_sum(ent, sb);
  if (tid == 0) {
    float var = (sq - total*total*(1.0f/(NT*NE))) * (1.0f/(NT*NE - 1));
    float stdv = sqrtf(fmaxf(var, 0.f));
    float ment = 0.f;
    #pragma unroll
    for (int e2 = 0; e2 < NE; ++e2) ment += out[ENT_OFF + e2];
    ment *= (1.0f/NE);
    out[AUX_OFF] = 0.5f*(stdv + ent) + 0.01f*ment;
  }
}

// ---------------- launch ------------------------------------------------------
extern "C" void kernel_launch(void* const* d_in, const int* in_sizes, int n_in,
                              void* d_out, int out_size, void* d_ws, size_t ws_size,
                              hipStream_t stream) {
  const float* h  = (const float*)d_in[0];
  const float* ce = (const float*)d_in[1];
  const float* gn = (const float*)d_in[2];
  const float* ca = (const float*)d_in[3];
  const float* fi = (const float*)d_in[4];
  const float* W1 = (const float*)d_in[5];
  const float* b1 = (const float*)d_in[6];
  const float* W2 = (const float*)d_in[7];
  const float* b2 = (const float*)d_in[8];
  float* out = (float*)d_out;
  char* ws = (char*)d_ws;
  // ws layout (bytes)
  bf16*  w1t      = (bf16*)(ws);                 // [E][DH][DIN] bf16: 10,485,760
  bf16*  w2t      = (bf16*)(ws + 10485760);      // [E][DOUT][DH] bf16: 2,097,152
  float* imp      = (float*)(ws + 12582912);     // [E][DIN]: 20,480
  float* anch     = (float*)(ws + 12603392);     // [E][CODE]: 8,192
  float* ew       = (float*)(ws + 12611584);     // [B][T][E]: 262,144
  float* counts   = (float*)(ws + 12873728);     // [T*E]: 32,768
  float* partials = (float*)(ws + 12906496);     // [32]

  k_imp<<<dim3(8), dim3(256), 0, stream>>>(fi, imp, out);
  k_anchor_div<<<dim3(1), dim3(256), 0, stream>>>(ca, fi, anch, out);
  k_transpose<<<dim3(16, 10, 8), dim3(256), 0, stream>>>(W1, w1t, 640, 1024);
  k_transpose<<<dim3(2, 16, 8), dim3(256), 0, stream>>>(W2, w2t, 1024, 128);
  k_router<<<dim3(2048), dim3(256), 0, stream>>>(ce, gn, anch, ew);
  k_main<<<dim3(1024), dim3(512), 0, stream>>>(h, w1t, w2t, imp, b1, b2, ew, out);
  k_counts<<<dim3(32), dim3(256), 0, stream>>>(ew, counts, partials);
  k_aux<<<dim3(1), dim3(256), 0, stream>>>(counts, partials, out);
}

// Round 2
// 344.270 us; speedup vs baseline: 1.4626x; 1.4626x over previous
//
#include <hip/hip_runtime.h>
#include <math.h>

#define DIN 640
#define DH 1024
#define DOUT 128
#define CODEDIM 256
#define NE 8
#define NB 8
#define NT 1024
#define TAU_INV 10.0f
#define FEPS 1e-8f

// out layout: full_output[8*1024*1024], aux[1], div[1], ent[8], mean[8], std[8]
#define AUX_OFF  8388608
#define DIV_OFF  8388609
#define ENT_OFF  8388610
#define MEAN_OFF 8388618
#define STD_OFF  8388626

typedef __bf16 bf16;
typedef bf16 bf16x4 __attribute__((ext_vector_type(4)));
typedef bf16 bf16x8 __attribute__((ext_vector_type(8)));
typedef float f32x16 __attribute__((ext_vector_type(16)));

// ---------------- block reduction helpers (blockDim multiple of 64) ----------
__device__ __forceinline__ float blk_sum(float v, float* sb) {
  #pragma unroll
  for (int o = 32; o > 0; o >>= 1) v += __shfl_down(v, o, 64);
  __syncthreads();
  if ((threadIdx.x & 63) == 0) sb[threadIdx.x >> 6] = v;
  __syncthreads();
  float tot = 0.f;
  int nw = blockDim.x >> 6;
  for (int i = 0; i < nw; ++i) tot += sb[i];
  return tot;
}

__device__ __forceinline__ float blk_max(float v, float* sb) {
  #pragma unroll
  for (int o = 32; o > 0; o >>= 1) v = fmaxf(v, __shfl_down(v, o, 64));
  __syncthreads();
  if ((threadIdx.x & 63) == 0) sb[threadIdx.x >> 6] = v;
  __syncthreads();
  float m = -3.0e38f;
  int nw = blockDim.x >> 6;
  for (int i = 0; i < nw; ++i) m = fmaxf(m, sb[i]);
  return m;
}

// ---------------- importance softmax + entropy/mean/std ---------------------
__global__ void k_imp(const float* __restrict__ fi, float* __restrict__ imp,
                      float* __restrict__ out) {
  __shared__ float sb[8];
  int e = blockIdx.x, tid = threadIdx.x;
  int d2v = tid + 512;
  float v0 = fi[e*DIN + tid] * 2.0f;          // /temp, temp = 0.5
  float v1 = fi[e*DIN + tid + 256] * 2.0f;
  float v2 = (d2v < DIN) ? fi[e*DIN + d2v] * 2.0f : -3.0e38f;
  float m = blk_max(fmaxf(v0, fmaxf(v1, v2)), sb);
  float e0 = expf(v0 - m), e1 = expf(v1 - m);
  float e2 = (d2v < DIN) ? expf(v2 - m) : 0.f;
  float s = blk_sum(e0 + e1 + e2, sb);
  float inv = 1.0f / s;
  float p0 = e0*inv, p1 = e1*inv, p2 = e2*inv;
  imp[e*DIN + tid] = p0;
  imp[e*DIN + tid + 256] = p1;
  if (d2v < DIN) imp[e*DIN + d2v] = p2;
  float ok2 = (d2v < DIN) ? 1.f : 0.f;
  float sp  = p0 + p1 + ok2*p2;
  float sp2 = p0*p0 + p1*p1 + ok2*p2*p2;
  float se  = p0*logf(p0 + FEPS) + p1*logf(p1 + FEPS) + ok2*p2*logf(p2 + FEPS);
  sp  = blk_sum(sp, sb);
  sp2 = blk_sum(sp2, sb);
  se  = blk_sum(se, sb);
  if (tid == 0) {
    out[ENT_OFF + e]  = -se;
    out[MEAN_OFF + e] = sp * (1.0f/DIN);
    float var = (sp2 - sp*sp*(1.0f/DIN)) * (1.0f/(DIN-1));
    out[STD_OFF + e]  = sqrtf(fmaxf(var, 0.f));
  }
}

// ---------------- anchor normalize + diversity loss --------------------------
__global__ void k_anchor_div(const float* __restrict__ ca, const float* __restrict__ fi,
                             float* __restrict__ anch, float* __restrict__ out) {
  __shared__ float sb[8];
  __shared__ float sd[256];
  int tid = threadIdx.x;
  for (int e = 0; e < NE; ++e) {
    float x = ca[e*CODEDIM + tid];
    float ss = blk_sum(x*x, sb);
    anch[e*CODEDIM + tid] = x / fmaxf(sqrtf(ss), 1e-12f);
  }
  // diversity: sim = fi @ fi^T, off-diag squared sum / 56
  int p = tid >> 2, q = tid & 3;     // pair p in 0..63, quarter q
  int i = p >> 3, j = p & 7;
  float dot = 0.f;
  for (int d = q*160; d < q*160 + 160; ++d) dot += fi[i*DIN + d] * fi[j*DIN + d];
  sd[tid] = dot;
  __syncthreads();
  if (tid < 64) {
    float s = sd[tid*4] + sd[tid*4+1] + sd[tid*4+2] + sd[tid*4+3];
    int ii = tid >> 3, jj = tid & 7;
    float val = (ii != jj) ? s*s : 0.f;
    #pragma unroll
    for (int o = 32; o > 0; o >>= 1) val += __shfl_down(val, o, 64);
    if (tid == 0) out[DIV_OFF] = val * (1.0f/56.0f);
  }
}

// ---------------- tiled transpose + f32->bf16: src[e][R][C] -> dst[e][C][R] --
__global__ void k_transpose(const float* __restrict__ src, bf16* __restrict__ dst,
                            int R, int C) {
  __shared__ float tile[64][65];
  int c0 = blockIdx.x*64, r0 = blockIdx.y*64;
  int ee = blockIdx.z;
  const float* s = src + (size_t)ee*R*C;
  bf16* d = dst + (size_t)ee*C*R;
  int tx = threadIdx.x & 63, ty = threadIdx.x >> 6;
  #pragma unroll
  for (int p = 0; p < 16; ++p) {
    int r = p*4 + ty;
    tile[r][tx] = s[(size_t)(r0 + r)*C + c0 + tx];
  }
  __syncthreads();
  #pragma unroll
  for (int p = 0; p < 16; ++p) {
    int cr = p*4 + ty;
    d[(size_t)(c0 + cr)*R + r0 + tx] = (bf16)tile[tx][cr];
  }
}

// ---------------- router: cosine logits + gumbel softmax ---------------------
__global__ void k_router(const float* __restrict__ ce, const float* __restrict__ gn,
                         const float* __restrict__ anch, float* __restrict__ ew) {
  __shared__ float anc[NE*CODEDIM];
  int tid = threadIdx.x;
  for (int i2 = tid; i2 < NE*CODEDIM; i2 += 256) anc[i2] = anch[i2];
  __syncthreads();
  int wv = tid >> 6, lane = tid & 63;
  int token = blockIdx.x*4 + wv;
  float4 x = *(const float4*)(ce + (size_t)token*CODEDIM + lane*4);
  float ss = x.x*x.x + x.y*x.y + x.z*x.z + x.w*x.w;
  #pragma unroll
  for (int o = 1; o < 64; o <<= 1) ss += __shfl_xor(ss, o, 64);
  float inv = 1.0f / fmaxf(sqrtf(ss), 1e-12f);
  const float* g = gn + (size_t)token*NE;
  float z[8];
  float m = -3.0e38f;
  #pragma unroll
  for (int e2 = 0; e2 < NE; ++e2) {
    const float* a = anc + e2*CODEDIM + lane*4;
    float d = x.x*a[0] + x.y*a[1] + x.z*a[2] + x.w*a[3];
    #pragma unroll
    for (int o = 1; o < 64; o <<= 1) d += __shfl_xor(d, o, 64);
    z[e2] = (d*inv + g[e2]) * TAU_INV;
    m = fmaxf(m, z[e2]);
  }
  float ssum = 0.f;
  float pz[8];
  #pragma unroll
  for (int e2 = 0; e2 < NE; ++e2) { pz[e2] = expf(z[e2] - m); ssum += pz[e2]; }
  float num = 0.f;
  #pragma unroll
  for (int e2 = 0; e2 < NE; ++e2) num = (lane == e2) ? pz[e2] : num;  // static idx
  if (lane < NE) ew[(size_t)token*NE + lane] = num / ssum;
}

// ---------------- fused per-(b,e,64-token-tile) MoE MLP ----------------------
// 512 threads = 8 waves. GEMM1: each wave owns 32 H-cols x 64 rows (two 32x32
// tiles sharing one B fragment -> W1 read exactly once per block). DH done in
// 4 passes of 256 cols; H double-buffered in LDS (one barrier per pass).
// GEMM2: wave w -> row-tile (w>>2), col-tile (w&3), K = pass's 256 H-cols.
// e = bid&7 pins each expert to one XCD -> weights L2-resident.
__global__ __launch_bounds__(512, 2)
void k_main(const float* __restrict__ h, const bf16* __restrict__ w1t,
            const bf16* __restrict__ w2t, const float* __restrict__ imp,
            const float* __restrict__ b1, const float* __restrict__ b2,
            const float* __restrict__ ew, float* __restrict__ out) {
  __shared__ bf16 XsF[64*DIN];       // 80 KiB, XOR-swizzled rows (stride 1280B)
  __shared__ bf16 HsF[2][64*256];    // 64 KiB, double-buffered, swizzled
  __shared__ float imp_s[DIN];
  int bid = blockIdx.x;
  int e = bid & 7, tt = (bid >> 3) & 15, b = bid >> 7;
  int t0 = tt * 64;
  int tid = threadIdx.x;
  for (int i = tid; i < DIN; i += 512) imp_s[i] = imp[e*DIN + i];
  __syncthreads();
  // stage X = h * importance as bf16 (coalesced float4 reads)
  const float* hb = h + (size_t)(b*NT + t0) * DIN;
  for (int i = tid; i < 64*(DIN/4); i += 512) {
    int row = i / (DIN/4);
    int c4 = (i - row*(DIN/4)) * 4;
    float4 v = *(const float4*)(hb + (size_t)row*DIN + c4);
    bf16x4 bv;
    bv[0] = (bf16)(v.x * imp_s[c4]);
    bv[1] = (bf16)(v.y * imp_s[c4+1]);
    bv[2] = (bf16)(v.z * imp_s[c4+2]);
    bv[3] = (bf16)(v.w * imp_s[c4+3]);
    unsigned wb = (unsigned)(row*(DIN*2) + c4*2) ^ ((unsigned)(row & 7) << 4);
    *(bf16x4*)((char*)XsF + wb) = bv;
  }
  __syncthreads();
  int lane = tid & 63, w = tid >> 6;
  int l31 = lane & 31, hh = lane >> 5;
  int rt = w >> 2, ct = w & 3;
  unsigned xr = (unsigned)(l31 & 7) << 4;
  unsigned abaseX = (unsigned)(l31*(DIN*2) + 16*hh);        // row = l31 (tile a)
  unsigned abaseH = (unsigned)((32*rt + l31)*512 + 16*hh);  // GEMM2 A rows
  int colo = ct*32 + l31;                                   // GEMM2 out col
  f32x16 acc2 = {};
  const bf16* w1e = w1t + (size_t)e*DH*DIN;
  const bf16* w2e = w2t + (size_t)e*DOUT*DH;
  const bf16* pB2base = w2e + (size_t)colo*DH + 8*hh;
  for (int p = 0; p < 4; ++p) {
    int colH = p*256 + w*32 + l31;            // this wave's GEMM1 col
    f32x16 acc1a = {}, acc1b = {};
    const bf16* pB = w1e + (size_t)colH*DIN + 8*hh;
    #pragma unroll 4
    for (int ks = 0; ks < DIN/16; ++ks) {
      unsigned a0 = (abaseX + 32u*ks) ^ xr;
      bf16x8 af0 = *(const bf16x8*)((const char*)XsF + a0);
      bf16x8 af1 = *(const bf16x8*)((const char*)XsF + a0 + 32u*(DIN*2)); // rows+32, same xr
      bf16x8 bfr = *(const bf16x8*)(pB + 16*ks);
      acc1a = __builtin_amdgcn_mfma_f32_32x32x16_bf16(af0, bfr, acc1a, 0, 0, 0);
      acc1b = __builtin_amdgcn_mfma_f32_32x32x16_bf16(af1, bfr, acc1b, 0, 0, 0);
    }
    // epilogue: +b1, exact GELU, bf16 -> Hs[p&1] (swizzled)
    float bb1 = b1[e*DH + colH];
    bf16* Hb = HsF[p & 1];
    int colc2 = (w*32 + l31)*2;
    #pragma unroll
    for (int r = 0; r < 16; ++r) {
      int rowa = (r & 3) + 8*(r >> 2) + 4*hh;     // 0..31 (tile a)
      unsigned wb = (unsigned)(rowa*512 + colc2) ^ ((unsigned)(rowa & 7) << 4);
      float xa = acc1a[r] + bb1;
      float xb = acc1b[r] + bb1;
      float ga = 0.5f * xa * (1.0f + erff(xa * 0.70710678118654752f));
      float gb = 0.5f * xb * (1.0f + erff(xb * 0.70710678118654752f));
      *(bf16*)((char*)Hb + wb) = (bf16)ga;
      *(bf16*)((char*)Hb + wb + 32*512) = (bf16)gb;  // rows+32, same swizzle bits
    }
    __syncthreads();
    // GEMM2 partial: K = this pass's 256 H-cols
    const bf16* pB2 = pB2base + p*256;
    #pragma unroll 4
    for (int kk = 0; kk < 16; ++kk) {
      bf16x8 a2 = *(const bf16x8*)((const char*)Hb + ((abaseH + 32u*kk) ^ xr));
      bf16x8 b2r = *(const bf16x8*)(pB2 + 16*kk);
      acc2 = __builtin_amdgcn_mfma_f32_32x32x16_bf16(a2, b2r, acc2, 0, 0, 0);
    }
  }
  float bb2 = b2[e*DOUT + colo];
  #pragma unroll
  for (int r = 0; r < 16; ++r) {
    int rowa = 32*rt + (r & 3) + 8*(r >> 2) + 4*hh;
    int t = t0 + rowa;
    float gate = ew[(size_t)(b*NT + t)*NE + e];
    out[(size_t)(b*NT + t)*(NE*DOUT) + e*DOUT + colo] = (acc2[r] + bb2) * gate;
  }
}

// ---------------- expert counts + partial sums --------------------------------
__global__ void k_counts(const float* __restrict__ ew, float* __restrict__ counts,
                         float* __restrict__ partials) {
  __shared__ float sb[4];
  int g2 = blockIdx.x*256 + threadIdx.x;   // (t,e) flat, 0..8191
  float c = 0.f;
  #pragma unroll
  for (int b = 0; b < NB; ++b) c += ew[b*(NT*NE) + g2];
  counts[g2] = c;
  float tot = blk_sum(c, sb);
  if (threadIdx.x == 0) partials[blockIdx.x] = tot;
}

// ---------------- aux loss ----------------------------------------------------
__global__ void k_aux(const float* __restrict__ counts, const float* __restrict__ partials,
                      float* __restrict__ out) {
  __shared__ float sb[4];
  int tid = threadIdx.x;
  float pv = (tid < 32) ? partials[tid] : 0.f;
  float total = blk_sum(pv, sb);
  float invt = 1.0f / (total + FEPS);
  float sq = 0.f, ent = 0.f;
  for (int i2 = tid; i2 < NT*NE; i2 += 256) {
    float c = counts[i2];
    sq += c*c;
    float ld = c * invt;
    ent -= ld * logf(ld + FEPS);
  }
  sq = blk_sum(sq, sb);
  ent = blk_sum(ent, sb);
  if (tid == 0) {
    float var = (sq - total*total*(1.0f/(NT*NE))) * (1.0f/(NT*NE - 1));
    float stdv = sqrtf(fmaxf(var, 0.f));
    float ment = 0.f;
    #pragma unroll
    for (int e2 = 0; e2 < NE; ++e2) ment += out[ENT_OFF + e2];
    ment *= (1.0f/NE);
    out[AUX_OFF] = 0.5f*(stdv + ent) + 0.01f*ment;
  }
}

// ---------------- launch ------------------------------------------------------
extern "C" void kernel_launch(void* const* d_in, const int* in_sizes, int n_in,
                              void* d_out, int out_size, void* d_ws, size_t ws_size,
                              hipStream_t stream) {
  const float* h  = (const float*)d_in[0];
  const float* ce = (const float*)d_in[1];
  const float* gn = (const float*)d_in[2];
  const float* ca = (const float*)d_in[3];
  const float* fi = (const float*)d_in[4];
  const float* W1 = (const float*)d_in[5];
  const float* b1 = (const float*)d_in[6];
  const float* W2 = (const float*)d_in[7];
  const float* b2 = (const float*)d_in[8];
  float* out = (float*)d_out;
  char* ws = (char*)d_ws;
  // ws layout (bytes)
  bf16*  w1t      = (bf16*)(ws);                 // [E][DH][DIN] bf16: 10,485,760
  bf16*  w2t      = (bf16*)(ws + 10485760);      // [E][DOUT][DH] bf16: 2,097,152
  float* imp      = (float*)(ws + 12582912);     // [E][DIN]: 20,480
  float* anch     = (float*)(ws + 12603392);     // [E][CODE]: 8,192
  float* ew       = (float*)(ws + 12611584);     // [B][T][E]: 262,144
  float* counts   = (float*)(ws + 12873728);     // [T*E]: 32,768
  float* partials = (float*)(ws + 12906496);     // [32]

  k_imp<<<dim3(8), dim3(256), 0, stream>>>(fi, imp, out);
  k_anchor_div<<<dim3(1), dim3(256), 0, stream>>>(ca, fi, anch, out);
  k_transpose<<<dim3(16, 10, 8), dim3(256), 0, stream>>>(W1, w1t, 640, 1024);
  k_transpose<<<dim3(2, 16, 8), dim3(256), 0, stream>>>(W2, w2t, 1024, 128);
  k_router<<<dim3(2048), dim3(256), 0, stream>>>(ce, gn, anch, ew);
  k_main<<<dim3(1024), dim3(512), 0, stream>>>(h, w1t, w2t, imp, b1, b2, ew, out);
  k_counts<<<dim3(32), dim3(256), 0, stream>>>(ew, counts, partials);
  k_aux<<<dim3(1), dim3(256), 0, stream>>>(counts, partials, out);
}